// Round 10
// baseline (201.215 us; speedup 1.0000x reference)
//
#include <hip/hip_runtime.h>
#include <math.h>

// EquivariantWSSHead: V=100000 vertices, E=1600000 edges, C0=C1=16.
//
// R1: 4 fp global atomics/edge -> 321us.  R2: 1 int atomic/edge -> 67us.
// R3: binning, bad shapes. 258us.  R4: fused scatter, 202us.
// R5/R6: ext_vector/nontemporal kernel constructs crash the container.
// R7: bf16 table+payload, 199us. bin-major payload = cross-XCD false share.
// R8: 57KB LDS payload stage -> container crash (construct bisected in R9).
// R9: fused count+scan+compute+scatter, block-private payload. 183us.
//     WRITE still 55MB: random-in-time 8B stores + streaming arrays evict
//     partial lines from L2. precompute+bucket ~130us (strided scalar loads;
//     serial 64B run walks).
// R10: stream everything:
//     - scatter: bin-sort 2B edge indices in LDS (12.5KB), pass2 emits
//       payload SEQUENTIALLY (full-line stores, no write amplification)
//     - precompute: LDS-stage x rows via coalesced float4 loads
//     - bucket: scan run lengths, expand addrlist in LDS, parallel entry
//       walk -> coalesced payload reads
//
// Per-edge math factors through per-source-vertex dot products:
//   u1.w = cg*(a.w) - sg*(b.w),  u2.w = sg*(a.w) + cg*(b.w)
// so precompute makes a 16-bf16 (32B) table line per vertex (3.2MB,
// L2/LLC-resident); each edge gathers exactly one half-line.

#define VB 128           // vertices per bucket
#define VB_SHIFT 7
#define BIGT 1024        // threads for scatter_all
#define MAXNB 1024       // NB = ceil(V/128) <= 1024 for V <= 131072
#define CHUNK 6250       // edges per scatter block
#define CHUNKP 6272      // padded entries (8B each) -> 64B-aligned regions
#define MAXRB 256        // max scatter blocks (runs per bucket)
#define MAXN 4096        // bucket addrlist capacity (mean 2046, sigma 45)

typedef unsigned int uint32;

static __device__ __forceinline__ uint32 f2bf(float f) {
    uint32 u = __float_as_uint(f);
    return (u + 0x7FFFu + ((u >> 16) & 1u)) >> 16;   // RNE to bf16
}
static __device__ __forceinline__ uint32 pack2(float lo, float hi) {
    return f2bf(lo) | (f2bf(hi) << 16);
}
static __device__ __forceinline__ float bf_lo(uint32 u) {
    return __uint_as_float(u << 16);
}
static __device__ __forceinline__ float bf_hi(uint32 u) {
    return __uint_as_float(u & 0xFFFF0000u);
}

// K1: per-vertex dot-product table. x rows staged through LDS so global
// reads are coalesced float4 (thread-private 192B rows are strided).
__global__ __launch_bounds__(256)
void precompute_kernel(const float* __restrict__ x,
                       const float* __restrict__ w_self0,
                       const float* __restrict__ w_n00,
                       const float* __restrict__ w_n10,
                       const float* __restrict__ w_self11,
                       const float* __restrict__ w_n01,
                       const float* __restrict__ w_n11,
                       uint32* __restrict__ table,   // 8 u32/vertex
                       float* __restrict__ selfbuf,
                       int V) {
    __shared__ float4 stage4[256 * 12];   // 48KB: 256 rows x 48 floats
    int v0 = blockIdx.x * 256;
    int nv = min(256, V - v0);
    if (nv <= 0) return;
    const float4* x4 = (const float4*)(x + (size_t)v0 * 48);
    int n4 = nv * 12;
    for (int j = threadIdx.x; j < n4; j += 256) stage4[j] = x4[j];
    __syncthreads();

    int t = threadIdx.x;
    if (t >= nv) return;
    int v = v0 + t;
    const float* xr = (const float*)stage4 + t * 48;   // 2-way LDS alias: free
    float d00 = 0.f, aw0 = 0.f, bw0 = 0.f, aw1 = 0.f, bw1 = 0.f;
    float d01a = 0.f, d01b = 0.f;
    float aP = 0.f, bP = 0.f, aQ = 0.f, bQ = 0.f;
    float aR = 0.f, bR = 0.f, aS = 0.f, bS = 0.f;
    float selfmag = 0.f, t1s = 0.f, t2s = 0.f;
#pragma unroll
    for (int i = 0; i < 16; ++i) {
        float x0 = xr[i];
        float a  = xr[16 + 2 * i];
        float b  = xr[17 + 2 * i];
        d00     += x0 * w_n00[i];
        selfmag += x0 * w_self0[i];
        d01a    += x0 * w_n01[i * 2 + 0];
        d01b    += x0 * w_n01[i * 2 + 1];
        float w0 = w_n10[i * 2 + 0], w1 = w_n10[i * 2 + 1];
        aw0 += a * w0;  bw0 += b * w0;
        aw1 += a * w1;  bw1 += b * w1;
        float p = w_n11[i * 4 + 0], q = w_n11[i * 4 + 1];
        float r = w_n11[i * 4 + 2], s = w_n11[i * 4 + 3];
        aP += a * p;  bP += b * p;
        aQ += a * q;  bQ += b * q;
        aR += a * r;  bR += b * r;
        aS += a * s;  bS += b * s;
        float sa_ = w_self11[i * 2 + 0], sb_ = w_self11[i * 2 + 1];
        t1s += a * sa_ - b * sb_;
        t2s += b * sa_ + a * sb_;
    }
    uint4 w0, w1;
    w0.x = pack2(d00, aw0);  w0.y = pack2(bw0, aw1);
    w0.z = pack2(bw1, d01a); w0.w = pack2(d01b, aP);
    w1.x = pack2(bP, aQ);    w1.y = pack2(bQ, aR);
    w1.z = pack2(bR, aS);    w1.w = pack2(bS, 0.f);
    uint4* tp = (uint4*)(table + (size_t)v * 8);
    tp[0] = w0;  tp[1] = w1;
    float* sf = selfbuf + (size_t)v * 4;
    sf[0] = selfmag; sf[1] = t1s; sf[2] = t2s; sf[3] = 0.f;
}

// K2: histogram + scan + LDS index-sort + compute + SEQUENTIAL payload emit.
// runmat: NB+1 rows x nblk cols; row i col b = global start of (b, bin i)
// run; row NB = end of block b's region.
__global__ __launch_bounds__(BIGT)
void scatter_all_kernel(const int* __restrict__ src,
                        const int* __restrict__ dst,
                        const float* __restrict__ angles,
                        const float* __restrict__ transporters,
                        const uint32* __restrict__ table,
                        int* __restrict__ runmat,
                        uint2* __restrict__ payload,
                        int E, int NB, int nblk) {
    __shared__ int cnt_l[MAXNB];
    __shared__ int off_l[MAXNB];
    __shared__ unsigned short sorted[CHUNK];

    int b = blockIdx.x;
    int lo = b * CHUNK;
    int hi = min(E, lo + CHUNK);
    int nloc = hi - lo;

    for (int i = threadIdx.x; i < NB; i += BIGT) cnt_l[i] = 0;
    __syncthreads();

    // pass1: histogram this block's dst chunk (25KB window, L1/L2-hot)
    for (int e = lo + threadIdx.x; e < hi; e += BIGT)
        atomicAdd(&cnt_l[dst[e] >> VB_SHIFT], 1);
    __syncthreads();

    // inclusive scan (Hillis-Steele, NB <= 1024)
    if (threadIdx.x < NB) off_l[threadIdx.x] = cnt_l[threadIdx.x];
    __syncthreads();
    for (int stp = 1; stp < NB; stp <<= 1) {
        int vv = 0;
        if (threadIdx.x < NB && threadIdx.x >= stp)
            vv = off_l[threadIdx.x - stp];
        __syncthreads();
        if (threadIdx.x < NB) off_l[threadIdx.x] += vv;
        __syncthreads();
    }

    // runmat column b; cnt_l becomes LOCAL cursors
    int bCH = b * CHUNKP;
    if (threadIdx.x < NB) {
        int ex = off_l[threadIdx.x] - cnt_l[threadIdx.x];
        runmat[(size_t)threadIdx.x * nblk + b] = bCH + ex;
        cnt_l[threadIdx.x] = ex;
    }
    if (threadIdx.x == 0)
        runmat[(size_t)NB * nblk + b] = bCH + nloc;
    __syncthreads();

    // pass1.5: bin-sort local edge indices (2B each)
    for (int e = lo + threadIdx.x; e < hi; e += BIGT) {
        int bin = dst[e] >> VB_SHIFT;
        int pos = atomicAdd(&cnt_l[bin], 1);
        sorted[pos] = (unsigned short)(e - lo);
    }
    __syncthreads();

    // pass2: compute in bin order, emit payload sequentially (coalesced)
    for (int k = threadIdx.x; k < nloc; k += BIGT) {
        int e = lo + sorted[k];
        int d = dst[e];
        int dl = d & (VB - 1);
        int s = src[e];
        float ang = angles[e], trv = transporters[e];
        float st, ct, sg, cg;
        sincosf(ang, &st, &ct);
        sincosf(trv, &sg, &cg);
        float c2t = ct * ct - st * st;
        float s2t = 2.0f * st * ct;

        const uint4* tp = (const uint4*)(table + (size_t)s * 8);
        uint4 W0 = tp[0], W1 = tp[1];
        float d00 = bf_lo(W0.x), aw0 = bf_hi(W0.x);
        float bw0 = bf_lo(W0.y), aw1 = bf_hi(W0.y);
        float bw1 = bf_lo(W0.z), d01a = bf_hi(W0.z);
        float d01b = bf_lo(W0.w), aP = bf_hi(W0.w);
        float bP = bf_lo(W1.x), aQ = bf_hi(W1.x);
        float bQ = bf_lo(W1.y), aR = bf_hi(W1.y);
        float bR = bf_lo(W1.z), aS = bf_hi(W1.z);
        float bS = bf_lo(W1.w);

        float u1w0 = cg * aw0 - sg * bw0, u2w0 = sg * aw0 + cg * bw0;
        float u1w1 = cg * aw1 - sg * bw1, u2w1 = sg * aw1 + cg * bw1;
        float m0 = d00 + ct * u1w0 + st * u2w0 - st * u1w1 + ct * u2w1;

        float u1p = cg * aP - sg * bP, u2p = sg * aP + cg * bP;
        float u1q = cg * aQ - sg * bQ, u2q = sg * aQ + cg * bQ;
        float u1r = cg * aR - sg * bR, u2r = sg * aR + cg * bR;
        float u1s = cg * aS - sg * bS, u2s = sg * aS + cg * bS;

        float mv1 = d01a * ct - d01b * st
                  + u1p - u2q
                  + c2t * u1r + s2t * u2r
                  - (s2t * u1s - c2t * u2s);
        float mv2 = d01a * st + d01b * ct
                  + u2p + u1q
                  + s2t * u1r - c2t * u2r
                  + c2t * u1s + s2t * u2s;

        uint2 pl;
        pl.x = pack2(m0, mv1);
        pl.y = f2bf(mv2) | ((uint32)dl << 16);
        payload[bCH + k] = pl;
    }
}

// K3: one block per bucket. Expand the bucket's 256 runs into an LDS
// address list (parallel prefix over run lengths), then consume entries
// by global index -> coalesced payload reads.
__global__ __launch_bounds__(256)
void bucket_kernel(const uint2* __restrict__ payload,
                   const int* __restrict__ runmat,
                   const float* __restrict__ selfbuf,
                   const float* __restrict__ e1,
                   const float* __restrict__ e2,
                   float* __restrict__ out,
                   int V, int NB, int nblk) {
    __shared__ float acc[4][VB * 4];     // per-wave replicated
    __shared__ int stl[MAXRB];
    __shared__ int prefl[MAXRB];
    __shared__ int addrlist[MAXN];
    for (int i = threadIdx.x; i < 4 * VB * 4; i += 256)
        ((float*)acc)[i] = 0.f;

    int bin = blockIdx.x;
    int t = threadIdx.x;
    int st = 0, len = 0;
    if (t < nblk) {
        st  = runmat[(size_t)bin * nblk + t];
        len = runmat[(size_t)(bin + 1) * nblk + t] - st;
    }
    stl[t] = st;
    prefl[t] = len;
    __syncthreads();
    // inclusive scan over 256 run lengths
    for (int stp = 1; stp < 256; stp <<= 1) {
        int vv = (t >= stp) ? prefl[t - stp] : 0;
        __syncthreads();
        prefl[t] += vv;
        __syncthreads();
    }
    int ex = prefl[t] - len;
    for (int i = 0; i < len; ++i)
        addrlist[ex + i] = st + i;
    __syncthreads();
    int n = prefl[255];

    int wv = t >> 6;
    float* myacc = acc[wv];
    for (int k = t; k < n; k += 256) {
        uint2 pl = payload[addrlist[k]];
        float m0  = bf_lo(pl.x);
        float mv1 = bf_hi(pl.x);
        float mv2 = bf_lo(pl.y);
        int dl = pl.y >> 16;
        atomicAdd(&myacc[dl * 4 + 0], m0);
        atomicAdd(&myacc[dl * 4 + 1], mv1);
        atomicAdd(&myacc[dl * 4 + 2], mv2);
        atomicAdd(&myacc[dl * 4 + 3], 1.0f);
    }
    __syncthreads();
    if (t < VB) {
        int v = bin * VB + t;
        if (v < V) {
            float A0 = acc[0][t * 4 + 0] + acc[1][t * 4 + 0]
                     + acc[2][t * 4 + 0] + acc[3][t * 4 + 0];
            float A1 = acc[0][t * 4 + 1] + acc[1][t * 4 + 1]
                     + acc[2][t * 4 + 1] + acc[3][t * 4 + 1];
            float A2 = acc[0][t * 4 + 2] + acc[1][t * 4 + 2]
                     + acc[2][t * 4 + 2] + acc[3][t * 4 + 2];
            float A3 = acc[0][t * 4 + 3] + acc[1][t * 4 + 3]
                     + acc[2][t * 4 + 3] + acc[3][t * 4 + 3];
            float inv = 1.0f / fmaxf(A3, 1.0f);
            const float* sf = selfbuf + (size_t)v * 4;
            float mag = A0 * inv + sf[0];
            float t1  = A1 * inv + sf[1];
            float t2  = A2 * inv + sf[2];
            float scale = 2.0f / (1.0f + expf(-mag));
            float e1x = e1[v * 3 + 0], e1y = e1[v * 3 + 1], e1z = e1[v * 3 + 2];
            float e2x = e2[v * 3 + 0], e2y = e2[v * 3 + 1], e2z = e2[v * 3 + 2];
            out[v * 3 + 0] = (t1 * e1x + t2 * e2x) * scale;
            out[v * 3 + 1] = (t1 * e1y + t2 * e2y) * scale;
            out[v * 3 + 2] = (t1 * e1z + t2 * e2z) * scale;
        }
    }
}

extern "C" void kernel_launch(void* const* d_in, const int* in_sizes, int n_in,
                              void* d_out, int out_size, void* d_ws, size_t ws_size,
                              hipStream_t stream) {
    const float* x            = (const float*)d_in[0];
    const int*   edge_index   = (const int*)d_in[1];
    const float* angles       = (const float*)d_in[2];
    const float* transporters = (const float*)d_in[3];
    const float* e1           = (const float*)d_in[4];
    const float* e2           = (const float*)d_in[5];
    const float* w_self0      = (const float*)d_in[6];
    const float* w_n00        = (const float*)d_in[7];
    const float* w_n10        = (const float*)d_in[8];
    const float* w_self11     = (const float*)d_in[9];
    const float* w_n01        = (const float*)d_in[10];
    const float* w_n11        = (const float*)d_in[11];
    float* out = (float*)d_out;

    int V = in_sizes[0] / 48;
    int E = in_sizes[2];
    const int* src = edge_index;
    const int* dst = edge_index + E;

    int NB = (V + VB - 1) / VB;          // 782 for V=100000
    int nblk = (E + CHUNK - 1) / CHUNK;  // 256 for E=1.6M

    char* p = (char*)d_ws;
    int* runmat = (int*)p;  p += (size_t)(NB + 1) * nblk * 4;   // ~0.8MB
    uint32* table  = (uint32*)p;  p += (size_t)V * 8 * 4;       // bf16-packed
    float* selfbuf = (float*)p;   p += (size_t)V * 4 * 4;
    p = (char*)(((uintptr_t)p + 63) & ~(uintptr_t)63);
    uint2* payload = (uint2*)p;   // nblk * CHUNKP * 8 bytes (~12.9 MB)

    int gv = (V + 255) / 256;

    precompute_kernel<<<gv, 256, 0, stream>>>(x, w_self0, w_n00, w_n10,
                                              w_self11, w_n01, w_n11,
                                              table, selfbuf, V);
    scatter_all_kernel<<<nblk, BIGT, 0, stream>>>(src, dst, angles,
                                                  transporters, table,
                                                  runmat, payload,
                                                  E, NB, nblk);
    bucket_kernel<<<NB, 256, 0, stream>>>(payload, runmat, selfbuf,
                                          e1, e2, out, V, NB, nblk);
}

// Round 11
// 181.108 us; speedup vs baseline: 1.1110x; 1.1110x over previous
//
#include <hip/hip_runtime.h>
#include <math.h>

// EquivariantWSSHead: V=100000 vertices, E=1600000 edges, C0=C1=16.
//
// R1..R4: global-atomic designs floored ~70us/pass; binning + fused
//   compute-in-scatter got 202us.
// R5/R6/R8: ext_vector kernel params, nontemporal builtins, and the 57KB
//   LDS stage + register-payload-array construct all crash the container.
// R7: bf16 table+payload. 199us.
// R9: block-private payload regions, seq reads / random 8B writes:
//   F50/W55, scatter 51us, total 183.
// R10: LDS index-sort, random reads / seq writes: F127(!)/W19, 56us, 201.
//   Lesson: randomness must die in LDS, not move between global streams.
//   Arithmetic also shows precompute and bucket are each ~45-50us
//   (strided row reads ~4x amplified; both latency-starved at 12 waves/CU).
// R11: - scatter sorts 12B TUPLES (src|dl, ang, tr) in LDS: global reads
//        coalesced in pass1b, payload emit sequential in pass2.
//        CHUNK=3125, 512 blocks, LDS 45.5KB.
//      - precompute: 64-row LDS tile loop (12.3KB) -> coalesced float4
//        loads at full occupancy.
//      - bucket: 512 threads, 512-run scan, ascending addrlist consume.
//
// Per-edge math factors through per-source-vertex dot products:
//   u1.w = cg*(a.w) - sg*(b.w),  u2.w = sg*(a.w) + cg*(b.w)
// so precompute makes a 16-bf16 (32B) table line per vertex (3.2MB,
// L2/LLC-resident); each edge gathers exactly one half-line.

#define VB 128           // vertices per bucket
#define VB_SHIFT 7
#define BIGT 1024        // threads for scatter_all
#define MAXNB 1024       // NB = ceil(V/128) <= 1024 for V <= 131072
#define CHUNK 3125       // edges per scatter block
#define CHUNKP 3136      // padded entries (8B each) -> 64B-aligned regions
#define MAXRB 512        // max scatter blocks (runs per bucket)
#define MAXN 4096        // bucket addrlist capacity (mean 2046, sigma 45)
#define BUCT 512         // bucket threads

typedef unsigned int uint32;

static __device__ __forceinline__ uint32 f2bf(float f) {
    uint32 u = __float_as_uint(f);
    return (u + 0x7FFFu + ((u >> 16) & 1u)) >> 16;   // RNE to bf16
}
static __device__ __forceinline__ uint32 pack2(float lo, float hi) {
    return f2bf(lo) | (f2bf(hi) << 16);
}
static __device__ __forceinline__ float bf_lo(uint32 u) {
    return __uint_as_float(u << 16);
}
static __device__ __forceinline__ float bf_hi(uint32 u) {
    return __uint_as_float(u & 0xFFFF0000u);
}

// K1: per-vertex dot-product table. 64-row tiles staged through 12.3KB LDS
// (coalesced float4 global reads, full occupancy); wave `tile` computes.
__global__ __launch_bounds__(256)
void precompute_kernel(const float* __restrict__ x,
                       const float* __restrict__ w_self0,
                       const float* __restrict__ w_n00,
                       const float* __restrict__ w_n10,
                       const float* __restrict__ w_self11,
                       const float* __restrict__ w_n01,
                       const float* __restrict__ w_n11,
                       uint32* __restrict__ table,   // 8 u32/vertex
                       float* __restrict__ selfbuf,
                       int V) {
    __shared__ float4 stage4[64 * 12];   // 12.3KB: 64 rows x 48 floats
    int base = blockIdx.x * 256;
    int tid = threadIdx.x;
    int mywave = tid >> 6;
    int lane = tid & 63;
    for (int tile = 0; tile < 4; ++tile) {
        int v0 = base + tile * 64;
        int nv = min(64, V - v0);
        __syncthreads();
        if (nv > 0) {
            const float4* x4 = (const float4*)(x + (size_t)v0 * 48);
            int n4 = nv * 12;
            for (int j = tid; j < n4; j += 256) stage4[j] = x4[j];
        }
        __syncthreads();
        if (mywave != tile || lane >= nv) continue;
        int v = v0 + lane;
        const float* xr = (const float*)stage4 + lane * 48;
        float d00 = 0.f, aw0 = 0.f, bw0 = 0.f, aw1 = 0.f, bw1 = 0.f;
        float d01a = 0.f, d01b = 0.f;
        float aP = 0.f, bP = 0.f, aQ = 0.f, bQ = 0.f;
        float aR = 0.f, bR = 0.f, aS = 0.f, bS = 0.f;
        float selfmag = 0.f, t1s = 0.f, t2s = 0.f;
#pragma unroll
        for (int i = 0; i < 16; ++i) {
            float x0 = xr[i];
            float a  = xr[16 + 2 * i];
            float b  = xr[17 + 2 * i];
            d00     += x0 * w_n00[i];
            selfmag += x0 * w_self0[i];
            d01a    += x0 * w_n01[i * 2 + 0];
            d01b    += x0 * w_n01[i * 2 + 1];
            float w0 = w_n10[i * 2 + 0], w1 = w_n10[i * 2 + 1];
            aw0 += a * w0;  bw0 += b * w0;
            aw1 += a * w1;  bw1 += b * w1;
            float p = w_n11[i * 4 + 0], q = w_n11[i * 4 + 1];
            float r = w_n11[i * 4 + 2], s = w_n11[i * 4 + 3];
            aP += a * p;  bP += b * p;
            aQ += a * q;  bQ += b * q;
            aR += a * r;  bR += b * r;
            aS += a * s;  bS += b * s;
            float sa_ = w_self11[i * 2 + 0], sb_ = w_self11[i * 2 + 1];
            t1s += a * sa_ - b * sb_;
            t2s += b * sa_ + a * sb_;
        }
        uint4 w0, w1;
        w0.x = pack2(d00, aw0);  w0.y = pack2(bw0, aw1);
        w0.z = pack2(bw1, d01a); w0.w = pack2(d01b, aP);
        w1.x = pack2(bP, aQ);    w1.y = pack2(bQ, aR);
        w1.z = pack2(bR, aS);    w1.w = pack2(bS, 0.f);
        uint4* tp = (uint4*)(table + (size_t)v * 8);
        tp[0] = w0;  tp[1] = w1;
        float* sf = selfbuf + (size_t)v * 4;
        sf[0] = selfmag; sf[1] = t1s; sf[2] = t2s; sf[3] = 0.f;
    }
}

// K2: histogram + scan + LDS TUPLE-sort + compute + sequential payload emit.
// Tuple: tw0 = src | dl<<17 ; tw1 = angle bits ; tw2 = transporter bits.
// runmat: NB+1 rows x nblk cols; row i col b = global start of (b, bin i)
// run; row NB = end of block b's region.
__global__ __launch_bounds__(BIGT)
void scatter_all_kernel(const int* __restrict__ src,
                        const int* __restrict__ dst,
                        const float* __restrict__ angles,
                        const float* __restrict__ transporters,
                        const uint32* __restrict__ table,
                        int* __restrict__ runmat,
                        uint2* __restrict__ payload,
                        int E, int NB, int nblk) {
    __shared__ int cnt_l[MAXNB];
    __shared__ int off_l[MAXNB];
    __shared__ uint32 tw0[CHUNK];
    __shared__ uint32 tw1[CHUNK];
    __shared__ uint32 tw2[CHUNK];

    int b = blockIdx.x;
    int lo = b * CHUNK;
    int hi = min(E, lo + CHUNK);
    int nloc = hi - lo;

    for (int i = threadIdx.x; i < NB; i += BIGT) cnt_l[i] = 0;
    __syncthreads();

    // pass1a: histogram this block's dst chunk (12.5KB window, L1-hot)
    for (int e = lo + threadIdx.x; e < hi; e += BIGT)
        atomicAdd(&cnt_l[dst[e] >> VB_SHIFT], 1);
    __syncthreads();

    // inclusive scan (Hillis-Steele, NB <= 1024)
    if (threadIdx.x < NB) off_l[threadIdx.x] = cnt_l[threadIdx.x];
    __syncthreads();
    for (int stp = 1; stp < NB; stp <<= 1) {
        int vv = 0;
        if (threadIdx.x < NB && threadIdx.x >= stp)
            vv = off_l[threadIdx.x - stp];
        __syncthreads();
        if (threadIdx.x < NB) off_l[threadIdx.x] += vv;
        __syncthreads();
    }

    // runmat column b; cnt_l becomes LOCAL cursors
    int bCH = b * CHUNKP;
    if (threadIdx.x < NB) {
        int ex = off_l[threadIdx.x] - cnt_l[threadIdx.x];
        runmat[(size_t)threadIdx.x * nblk + b] = bCH + ex;
        cnt_l[threadIdx.x] = ex;
    }
    if (threadIdx.x == 0)
        runmat[(size_t)NB * nblk + b] = bCH + nloc;
    __syncthreads();

    // pass1b: coalesced reads of all 4 edge arrays; tuple -> sorted LDS slot
    for (int e = lo + threadIdx.x; e < hi; e += BIGT) {
        int d = dst[e];
        int bin = d >> VB_SHIFT;
        int dl = d & (VB - 1);
        int pos = atomicAdd(&cnt_l[bin], 1);
        tw0[pos] = (uint32)src[e] | ((uint32)dl << 17);
        tw1[pos] = __float_as_uint(angles[e]);
        tw2[pos] = __float_as_uint(transporters[e]);
    }
    __syncthreads();

    // pass2: compute in bin order from LDS, emit payload sequentially
    for (int k = threadIdx.x; k < nloc; k += BIGT) {
        uint32 w0i = tw0[k];
        int s  = (int)(w0i & 0x1FFFFu);
        int dl = (int)(w0i >> 17);
        float ang = __uint_as_float(tw1[k]);
        float trv = __uint_as_float(tw2[k]);
        float st, ct, sg, cg;
        sincosf(ang, &st, &ct);
        sincosf(trv, &sg, &cg);
        float c2t = ct * ct - st * st;
        float s2t = 2.0f * st * ct;

        const uint4* tp = (const uint4*)(table + (size_t)s * 8);
        uint4 W0 = tp[0], W1 = tp[1];
        float d00 = bf_lo(W0.x), aw0 = bf_hi(W0.x);
        float bw0 = bf_lo(W0.y), aw1 = bf_hi(W0.y);
        float bw1 = bf_lo(W0.z), d01a = bf_hi(W0.z);
        float d01b = bf_lo(W0.w), aP = bf_hi(W0.w);
        float bP = bf_lo(W1.x), aQ = bf_hi(W1.x);
        float bQ = bf_lo(W1.y), aR = bf_hi(W1.y);
        float bR = bf_lo(W1.z), aS = bf_hi(W1.z);
        float bS = bf_lo(W1.w);

        float u1w0 = cg * aw0 - sg * bw0, u2w0 = sg * aw0 + cg * bw0;
        float u1w1 = cg * aw1 - sg * bw1, u2w1 = sg * aw1 + cg * bw1;
        float m0 = d00 + ct * u1w0 + st * u2w0 - st * u1w1 + ct * u2w1;

        float u1p = cg * aP - sg * bP, u2p = sg * aP + cg * bP;
        float u1q = cg * aQ - sg * bQ, u2q = sg * aQ + cg * bQ;
        float u1r = cg * aR - sg * bR, u2r = sg * aR + cg * bR;
        float u1s = cg * aS - sg * bS, u2s = sg * aS + cg * bS;

        float mv1 = d01a * ct - d01b * st
                  + u1p - u2q
                  + c2t * u1r + s2t * u2r
                  - (s2t * u1s - c2t * u2s);
        float mv2 = d01a * st + d01b * ct
                  + u2p + u1q
                  + s2t * u1r - c2t * u2r
                  + c2t * u1s + s2t * u2s;

        uint2 pl;
        pl.x = pack2(m0, mv1);
        pl.y = f2bf(mv2) | ((uint32)dl << 16);
        payload[bCH + k] = pl;
    }
}

// K3: one block per bucket, 512 threads. Scan the bucket's 512 run lengths,
// expand ascending addrlist, consume coalesced; per-wave LDS accumulators.
__global__ __launch_bounds__(BUCT)
void bucket_kernel(const uint2* __restrict__ payload,
                   const int* __restrict__ runmat,
                   const float* __restrict__ selfbuf,
                   const float* __restrict__ e1,
                   const float* __restrict__ e2,
                   float* __restrict__ out,
                   int V, int NB, int nblk) {
    __shared__ float acc[8][VB * 4];     // per-wave replicated (16KB)
    __shared__ int stl[MAXRB];
    __shared__ int prefl[MAXRB];
    __shared__ int addrlist[MAXN];
    for (int i = threadIdx.x; i < 8 * VB * 4; i += BUCT)
        ((float*)acc)[i] = 0.f;

    int bin = blockIdx.x;
    int t = threadIdx.x;
    int st = 0, len = 0;
    if (t < nblk) {
        st  = runmat[(size_t)bin * nblk + t];
        len = runmat[(size_t)(bin + 1) * nblk + t] - st;
    }
    stl[t] = st;
    prefl[t] = len;
    __syncthreads();
    // inclusive scan over MAXRB run lengths
    for (int stp = 1; stp < MAXRB; stp <<= 1) {
        int vv = (t >= stp) ? prefl[t - stp] : 0;
        __syncthreads();
        prefl[t] += vv;
        __syncthreads();
    }
    int ex = prefl[t] - len;
    for (int i = 0; i < len; ++i)
        addrlist[ex + i] = st + i;
    __syncthreads();
    int n = prefl[MAXRB - 1];

    int wv = t >> 6;
    float* myacc = acc[wv];
    for (int k = t; k < n; k += BUCT) {
        uint2 pl = payload[addrlist[k]];
        float m0  = bf_lo(pl.x);
        float mv1 = bf_hi(pl.x);
        float mv2 = bf_lo(pl.y);
        int dl = pl.y >> 16;
        atomicAdd(&myacc[dl * 4 + 0], m0);
        atomicAdd(&myacc[dl * 4 + 1], mv1);
        atomicAdd(&myacc[dl * 4 + 2], mv2);
        atomicAdd(&myacc[dl * 4 + 3], 1.0f);
    }
    __syncthreads();
    if (t < VB) {
        int v = bin * VB + t;
        if (v < V) {
            float A0 = 0.f, A1 = 0.f, A2 = 0.f, A3 = 0.f;
#pragma unroll
            for (int w = 0; w < 8; ++w) {
                A0 += acc[w][t * 4 + 0];
                A1 += acc[w][t * 4 + 1];
                A2 += acc[w][t * 4 + 2];
                A3 += acc[w][t * 4 + 3];
            }
            float inv = 1.0f / fmaxf(A3, 1.0f);
            const float* sf = selfbuf + (size_t)v * 4;
            float mag = A0 * inv + sf[0];
            float t1  = A1 * inv + sf[1];
            float t2  = A2 * inv + sf[2];
            float scale = 2.0f / (1.0f + expf(-mag));
            float e1x = e1[v * 3 + 0], e1y = e1[v * 3 + 1], e1z = e1[v * 3 + 2];
            float e2x = e2[v * 3 + 0], e2y = e2[v * 3 + 1], e2z = e2[v * 3 + 2];
            out[v * 3 + 0] = (t1 * e1x + t2 * e2x) * scale;
            out[v * 3 + 1] = (t1 * e1y + t2 * e2y) * scale;
            out[v * 3 + 2] = (t1 * e1z + t2 * e2z) * scale;
        }
    }
}

extern "C" void kernel_launch(void* const* d_in, const int* in_sizes, int n_in,
                              void* d_out, int out_size, void* d_ws, size_t ws_size,
                              hipStream_t stream) {
    const float* x            = (const float*)d_in[0];
    const int*   edge_index   = (const int*)d_in[1];
    const float* angles       = (const float*)d_in[2];
    const float* transporters = (const float*)d_in[3];
    const float* e1           = (const float*)d_in[4];
    const float* e2           = (const float*)d_in[5];
    const float* w_self0      = (const float*)d_in[6];
    const float* w_n00        = (const float*)d_in[7];
    const float* w_n10        = (const float*)d_in[8];
    const float* w_self11     = (const float*)d_in[9];
    const float* w_n01        = (const float*)d_in[10];
    const float* w_n11        = (const float*)d_in[11];
    float* out = (float*)d_out;

    int V = in_sizes[0] / 48;
    int E = in_sizes[2];
    const int* src = edge_index;
    const int* dst = edge_index + E;

    int NB = (V + VB - 1) / VB;          // 782 for V=100000
    int nblk = (E + CHUNK - 1) / CHUNK;  // 512 for E=1.6M

    char* p = (char*)d_ws;
    int* runmat = (int*)p;  p += (size_t)(NB + 1) * nblk * 4;   // ~1.6MB
    uint32* table  = (uint32*)p;  p += (size_t)V * 8 * 4;       // bf16-packed
    float* selfbuf = (float*)p;   p += (size_t)V * 4 * 4;
    p = (char*)(((uintptr_t)p + 63) & ~(uintptr_t)63);
    uint2* payload = (uint2*)p;   // nblk * CHUNKP * 8 bytes (~12.9 MB)

    int gv = (V + 255) / 256;

    precompute_kernel<<<gv, 256, 0, stream>>>(x, w_self0, w_n00, w_n10,
                                              w_self11, w_n01, w_n11,
                                              table, selfbuf, V);
    scatter_all_kernel<<<nblk, BIGT, 0, stream>>>(src, dst, angles,
                                                  transporters, table,
                                                  runmat, payload,
                                                  E, NB, nblk);
    bucket_kernel<<<NB, BUCT, 0, stream>>>(payload, runmat, selfbuf,
                                           e1, e2, out, V, NB, nblk);
}

// Round 12
// 177.216 us; speedup vs baseline: 1.1354x; 1.0220x over previous
//
#include <hip/hip_runtime.h>
#include <math.h>

// EquivariantWSSHead: V=100000 vertices, E=1600000 edges, C0=C1=16.
//
// R1..R4: global-atomic designs floored ~70us/pass; binning+fusion 202us.
// R5/R6/R8: ext_vector kernel params, nontemporal builtins, 57KB LDS stage
//   + register payload arrays all crash the container. Keep constructs bland.
// R7/R9/R10: randomness must die in LDS, not move between global streams
//   (R9 random 8B writes W55; R10 random reads F127).
// R11: LDS tuple-sort: seq reads AND seq writes in scatter. 181us.
//   New wall: bucket 49us — runs of 4 entries (32B) random over 12.9MB,
//   FETCH 2.5x payload, HBM 710GB/s (8.9%), MLP~1. All 3 kernels ~45-49.
// R12: - VB 128->256 (NB=391): runs ~8 entries = 64B = one full line.
//      - bucket: run-per-thread (no addrlist), 4-wide batched uint2 loads
//        (MLP 4), per-wave LDS acc copies. LDS 32KB.
//      - scatter: dst staged in LDS on first read (kills 2nd global pass);
//        shfl two-level scan (3 barriers instead of 18).
//
// Per-edge math factors through per-source-vertex dot products:
//   u1.w = cg*(a.w) - sg*(b.w),  u2.w = sg*(a.w) + cg*(b.w)
// so precompute makes a 16-bf16 (32B) table line per vertex (3.2MB,
// L2/LLC-resident); each edge gathers exactly one half-line.

#define VB 256           // vertices per bucket
#define VB_SHIFT 8
#define BIGT 1024        // threads for scatter_all
#define MAXNB 400        // NB = ceil(V/256) = 391 for V=100000
#define CHUNK 3125       // edges per scatter block
#define CHUNKP 3136      // padded entries (8B each) -> 64B-aligned regions
#define BUCT 512         // bucket threads (= nblk runs per bucket)

typedef unsigned int uint32;

static __device__ __forceinline__ uint32 f2bf(float f) {
    uint32 u = __float_as_uint(f);
    return (u + 0x7FFFu + ((u >> 16) & 1u)) >> 16;   // RNE to bf16
}
static __device__ __forceinline__ uint32 pack2(float lo, float hi) {
    return f2bf(lo) | (f2bf(hi) << 16);
}
static __device__ __forceinline__ float bf_lo(uint32 u) {
    return __uint_as_float(u << 16);
}
static __device__ __forceinline__ float bf_hi(uint32 u) {
    return __uint_as_float(u & 0xFFFF0000u);
}

// K1: per-vertex dot-product table. 64-row tiles staged through 12.3KB LDS
// (coalesced float4 global reads); wave `tile` computes.
__global__ __launch_bounds__(256)
void precompute_kernel(const float* __restrict__ x,
                       const float* __restrict__ w_self0,
                       const float* __restrict__ w_n00,
                       const float* __restrict__ w_n10,
                       const float* __restrict__ w_self11,
                       const float* __restrict__ w_n01,
                       const float* __restrict__ w_n11,
                       uint32* __restrict__ table,   // 8 u32/vertex
                       float* __restrict__ selfbuf,
                       int V) {
    __shared__ float4 stage4[64 * 12];   // 12.3KB: 64 rows x 48 floats
    int base = blockIdx.x * 256;
    int tid = threadIdx.x;
    int mywave = tid >> 6;
    int lane = tid & 63;
    for (int tile = 0; tile < 4; ++tile) {
        int v0 = base + tile * 64;
        int nv = min(64, V - v0);
        __syncthreads();
        if (nv > 0) {
            const float4* x4 = (const float4*)(x + (size_t)v0 * 48);
            int n4 = nv * 12;
            for (int j = tid; j < n4; j += 256) stage4[j] = x4[j];
        }
        __syncthreads();
        if (mywave != tile || lane >= nv) continue;
        int v = v0 + lane;
        const float* xr = (const float*)stage4 + lane * 48;
        float d00 = 0.f, aw0 = 0.f, bw0 = 0.f, aw1 = 0.f, bw1 = 0.f;
        float d01a = 0.f, d01b = 0.f;
        float aP = 0.f, bP = 0.f, aQ = 0.f, bQ = 0.f;
        float aR = 0.f, bR = 0.f, aS = 0.f, bS = 0.f;
        float selfmag = 0.f, t1s = 0.f, t2s = 0.f;
#pragma unroll
        for (int i = 0; i < 16; ++i) {
            float x0 = xr[i];
            float a  = xr[16 + 2 * i];
            float b  = xr[17 + 2 * i];
            d00     += x0 * w_n00[i];
            selfmag += x0 * w_self0[i];
            d01a    += x0 * w_n01[i * 2 + 0];
            d01b    += x0 * w_n01[i * 2 + 1];
            float w0 = w_n10[i * 2 + 0], w1 = w_n10[i * 2 + 1];
            aw0 += a * w0;  bw0 += b * w0;
            aw1 += a * w1;  bw1 += b * w1;
            float p = w_n11[i * 4 + 0], q = w_n11[i * 4 + 1];
            float r = w_n11[i * 4 + 2], s = w_n11[i * 4 + 3];
            aP += a * p;  bP += b * p;
            aQ += a * q;  bQ += b * q;
            aR += a * r;  bR += b * r;
            aS += a * s;  bS += b * s;
            float sa_ = w_self11[i * 2 + 0], sb_ = w_self11[i * 2 + 1];
            t1s += a * sa_ - b * sb_;
            t2s += b * sa_ + a * sb_;
        }
        uint4 w0, w1;
        w0.x = pack2(d00, aw0);  w0.y = pack2(bw0, aw1);
        w0.z = pack2(bw1, d01a); w0.w = pack2(d01b, aP);
        w1.x = pack2(bP, aQ);    w1.y = pack2(bQ, aR);
        w1.z = pack2(bR, aS);    w1.w = pack2(bS, 0.f);
        uint4* tp = (uint4*)(table + (size_t)v * 8);
        tp[0] = w0;  tp[1] = w1;
        float* sf = selfbuf + (size_t)v * 4;
        sf[0] = selfmag; sf[1] = t1s; sf[2] = t2s; sf[3] = 0.f;
    }
}

// K2: histogram + shfl-scan + LDS tuple-sort + compute + sequential emit.
// Tuple: tw0 = src | dl<<17 ; tw1 = angle bits ; tw2 = transporter bits.
// runmat: NB+1 rows x nblk cols; row i col b = global start of (b, bin i)
// run; row NB = end of block b's region.
__global__ __launch_bounds__(BIGT)
void scatter_all_kernel(const int* __restrict__ src,
                        const int* __restrict__ dst,
                        const float* __restrict__ angles,
                        const float* __restrict__ transporters,
                        const uint32* __restrict__ table,
                        int* __restrict__ runmat,
                        uint2* __restrict__ payload,
                        int E, int NB, int nblk) {
    __shared__ int cnt_l[MAXNB];
    __shared__ int wsum[16];
    __shared__ uint32 dstl[CHUNK];
    __shared__ uint32 tw0[CHUNK];
    __shared__ uint32 tw1[CHUNK];
    __shared__ uint32 tw2[CHUNK];

    int b = blockIdx.x;
    int lo = b * CHUNK;
    int hi = min(E, lo + CHUNK);
    int nloc = hi - lo;
    int tid = threadIdx.x;
    int lane = tid & 63;
    int wv = tid >> 6;

    for (int i = tid; i < NB; i += BIGT) cnt_l[i] = 0;
    __syncthreads();

    // pass1a: single global read of dst -> LDS stage + histogram
    for (int i = tid; i < nloc; i += BIGT) {
        uint32 d = (uint32)dst[lo + i];
        dstl[i] = d;
        atomicAdd(&cnt_l[d >> VB_SHIFT], 1);
    }
    __syncthreads();

    // two-level exclusive scan over NB counts (3 barriers)
    int c = (tid < NB) ? cnt_l[tid] : 0;
    int incl = c;
#pragma unroll
    for (int d = 1; d < 64; d <<= 1) {
        int n = __shfl_up(incl, d);
        if (lane >= d) incl += n;
    }
    if (lane == 63) wsum[wv] = incl;
    __syncthreads();
    if (tid < 16) {
        int wval = wsum[tid], winc = wval;
#pragma unroll
        for (int d = 1; d < 16; d <<= 1) {
            int n = __shfl_up(winc, d);
            if (lane >= d) winc += n;
        }
        wsum[tid] = winc - wval;   // exclusive wave prefix
    }
    __syncthreads();
    int bCH = b * CHUNKP;
    if (tid < NB) {
        int ex = incl - c + wsum[wv];
        runmat[(size_t)tid * nblk + b] = bCH + ex;
        cnt_l[tid] = ex;           // local cursor
    }
    if (tid == 0)
        runmat[(size_t)NB * nblk + b] = bCH + nloc;
    __syncthreads();

    // pass1b: coalesced src/ang/tr reads; tuple -> bin-sorted LDS slot
    for (int i = tid; i < nloc; i += BIGT) {
        uint32 d = dstl[i];
        int bin = (int)(d >> VB_SHIFT);
        uint32 dl = d & (VB - 1);
        int pos = atomicAdd(&cnt_l[bin], 1);
        tw0[pos] = (uint32)src[lo + i] | (dl << 17);
        tw1[pos] = __float_as_uint(angles[lo + i]);
        tw2[pos] = __float_as_uint(transporters[lo + i]);
    }
    __syncthreads();

    // pass2: compute in bin order from LDS, emit payload sequentially
    for (int k = tid; k < nloc; k += BIGT) {
        uint32 w0i = tw0[k];
        int s  = (int)(w0i & 0x1FFFFu);
        int dl = (int)(w0i >> 17);
        float ang = __uint_as_float(tw1[k]);
        float trv = __uint_as_float(tw2[k]);
        float st, ct, sg, cg;
        sincosf(ang, &st, &ct);
        sincosf(trv, &sg, &cg);
        float c2t = ct * ct - st * st;
        float s2t = 2.0f * st * ct;

        const uint4* tp = (const uint4*)(table + (size_t)s * 8);
        uint4 W0 = tp[0], W1 = tp[1];
        float d00 = bf_lo(W0.x), aw0 = bf_hi(W0.x);
        float bw0 = bf_lo(W0.y), aw1 = bf_hi(W0.y);
        float bw1 = bf_lo(W0.z), d01a = bf_hi(W0.z);
        float d01b = bf_lo(W0.w), aP = bf_hi(W0.w);
        float bP = bf_lo(W1.x), aQ = bf_hi(W1.x);
        float bQ = bf_lo(W1.y), aR = bf_hi(W1.y);
        float bR = bf_lo(W1.z), aS = bf_hi(W1.z);
        float bS = bf_lo(W1.w);

        float u1w0 = cg * aw0 - sg * bw0, u2w0 = sg * aw0 + cg * bw0;
        float u1w1 = cg * aw1 - sg * bw1, u2w1 = sg * aw1 + cg * bw1;
        float m0 = d00 + ct * u1w0 + st * u2w0 - st * u1w1 + ct * u2w1;

        float u1p = cg * aP - sg * bP, u2p = sg * aP + cg * bP;
        float u1q = cg * aQ - sg * bQ, u2q = sg * aQ + cg * bQ;
        float u1r = cg * aR - sg * bR, u2r = sg * aR + cg * bR;
        float u1s = cg * aS - sg * bS, u2s = sg * aS + cg * bS;

        float mv1 = d01a * ct - d01b * st
                  + u1p - u2q
                  + c2t * u1r + s2t * u2r
                  - (s2t * u1s - c2t * u2s);
        float mv2 = d01a * st + d01b * ct
                  + u2p + u1q
                  + s2t * u1r - c2t * u2r
                  + c2t * u1s + s2t * u2s;

        uint2 pl;
        pl.x = pack2(m0, mv1);
        pl.y = f2bf(mv2) | ((uint32)dl << 16);
        payload[bCH + k] = pl;
    }
}

static __device__ __forceinline__ void addmsg(float* myacc, uint2 pl) {
    float m0  = bf_lo(pl.x);
    float mv1 = bf_hi(pl.x);
    float mv2 = bf_lo(pl.y);
    int dl = (int)(pl.y >> 16);
    atomicAdd(&myacc[dl * 4 + 0], m0);
    atomicAdd(&myacc[dl * 4 + 1], mv1);
    atomicAdd(&myacc[dl * 4 + 2], mv2);
    atomicAdd(&myacc[dl * 4 + 3], 1.0f);
}

// K3: one block per bucket; thread t owns scatter-block t's run (~8 entries
// = one 64B line), 4-wide batched loads (MLP 4), per-wave LDS acc copies.
__global__ __launch_bounds__(BUCT)
void bucket_kernel(const uint2* __restrict__ payload,
                   const int* __restrict__ runmat,
                   const float* __restrict__ selfbuf,
                   const float* __restrict__ e1,
                   const float* __restrict__ e2,
                   float* __restrict__ out,
                   int V, int NB, int nblk) {
    __shared__ float acc[8][VB * 4];     // 8 waves x 4KB = 32KB
    for (int i = threadIdx.x; i < 8 * VB * 4; i += BUCT)
        ((float*)acc)[i] = 0.f;
    __syncthreads();

    int bin = blockIdx.x;
    int t = threadIdx.x;
    float* myacc = acc[t >> 6];
    if (t < nblk) {
        int st = runmat[(size_t)bin * nblk + t];
        int en = runmat[(size_t)(bin + 1) * nblk + t];
        int k = st;
        for (; k + 4 <= en; k += 4) {
            uint2 p0 = payload[k + 0];
            uint2 p1 = payload[k + 1];
            uint2 p2 = payload[k + 2];
            uint2 p3 = payload[k + 3];
            addmsg(myacc, p0);
            addmsg(myacc, p1);
            addmsg(myacc, p2);
            addmsg(myacc, p3);
        }
        for (; k < en; ++k)
            addmsg(myacc, payload[k]);
    }
    __syncthreads();

    if (t < VB) {
        int v = bin * VB + t;
        if (v < V) {
            float A0 = 0.f, A1 = 0.f, A2 = 0.f, A3 = 0.f;
#pragma unroll
            for (int w = 0; w < 8; ++w) {
                A0 += acc[w][t * 4 + 0];
                A1 += acc[w][t * 4 + 1];
                A2 += acc[w][t * 4 + 2];
                A3 += acc[w][t * 4 + 3];
            }
            float inv = 1.0f / fmaxf(A3, 1.0f);
            const float* sf = selfbuf + (size_t)v * 4;
            float mag = A0 * inv + sf[0];
            float t1  = A1 * inv + sf[1];
            float t2  = A2 * inv + sf[2];
            float scale = 2.0f / (1.0f + expf(-mag));
            float e1x = e1[v * 3 + 0], e1y = e1[v * 3 + 1], e1z = e1[v * 3 + 2];
            float e2x = e2[v * 3 + 0], e2y = e2[v * 3 + 1], e2z = e2[v * 3 + 2];
            out[v * 3 + 0] = (t1 * e1x + t2 * e2x) * scale;
            out[v * 3 + 1] = (t1 * e1y + t2 * e2y) * scale;
            out[v * 3 + 2] = (t1 * e1z + t2 * e2z) * scale;
        }
    }
}

extern "C" void kernel_launch(void* const* d_in, const int* in_sizes, int n_in,
                              void* d_out, int out_size, void* d_ws, size_t ws_size,
                              hipStream_t stream) {
    const float* x            = (const float*)d_in[0];
    const int*   edge_index   = (const int*)d_in[1];
    const float* angles       = (const float*)d_in[2];
    const float* transporters = (const float*)d_in[3];
    const float* e1           = (const float*)d_in[4];
    const float* e2           = (const float*)d_in[5];
    const float* w_self0      = (const float*)d_in[6];
    const float* w_n00        = (const float*)d_in[7];
    const float* w_n10        = (const float*)d_in[8];
    const float* w_self11     = (const float*)d_in[9];
    const float* w_n01        = (const float*)d_in[10];
    const float* w_n11        = (const float*)d_in[11];
    float* out = (float*)d_out;

    int V = in_sizes[0] / 48;
    int E = in_sizes[2];
    const int* src = edge_index;
    const int* dst = edge_index + E;

    int NB = (V + VB - 1) / VB;          // 391 for V=100000
    int nblk = (E + CHUNK - 1) / CHUNK;  // 512 for E=1.6M

    char* p = (char*)d_ws;
    int* runmat = (int*)p;  p += (size_t)(NB + 1) * nblk * 4;   // ~0.8MB
    uint32* table  = (uint32*)p;  p += (size_t)V * 8 * 4;       // bf16-packed
    float* selfbuf = (float*)p;   p += (size_t)V * 4 * 4;
    p = (char*)(((uintptr_t)p + 63) & ~(uintptr_t)63);
    uint2* payload = (uint2*)p;   // nblk * CHUNKP * 8 bytes (~12.9 MB)

    int gv = (V + 255) / 256;

    precompute_kernel<<<gv, 256, 0, stream>>>(x, w_self0, w_n00, w_n10,
                                              w_self11, w_n01, w_n11,
                                              table, selfbuf, V);
    scatter_all_kernel<<<nblk, BIGT, 0, stream>>>(src, dst, angles,
                                                  transporters, table,
                                                  runmat, payload,
                                                  E, NB, nblk);
    bucket_kernel<<<NB, BUCT, 0, stream>>>(payload, runmat, selfbuf,
                                           e1, e2, out, V, NB, nblk);
}